// Round 5
// baseline (355.757 us; speedup 1.0000x reference)
//
#include <hip/hip_runtime.h>
#include <cstddef>

#define G 64
#define NPG 1024
#define NNODES 65536
#define NEDGE 1048576
#define CCAP 36                // per-node LDS neighbor capacity; true deg ~Poisson(16), P(>36)~1e-6/node; overflow exact via ovl_s
#define HSTR 20                // padded LDS row stride for h (floats); 80B rows, 16B aligned
#define ZTR 1028               // transposed z-tile d-row stride (floats); 16B-aligned, bank-staggered
#define ADJ_ELEMS 67108864ull  // 64*1024*1024
#define BM_WORDS 2097152       // 64 graphs * 1024 dst-rows * 32 words (src bits) = 8 MB
#define DCAP 1024              // per-graph dup-list capacity (expected ~131, sigma ~11)

typedef float f32x4 __attribute__((ext_vector_type(4)));
typedef float f32x2 __attribute__((ext_vector_type(2)));
typedef unsigned u32x4 __attribute__((ext_vector_type(4)));

// ---------------- K1: zero bitmap + dup counters + accumulators ----------------
__global__ __launch_bounds__(1024) void k_init(unsigned* __restrict__ bm2,
                                               int* __restrict__ dupcnt,
                                               float* __restrict__ acc) {
  int i = blockIdx.x * 1024 + threadIdx.x;
  if (i < G) dupcnt[i] = 0;
  if (i < 2) acc[i] = 0.0f;
  u32x4 z = {0u, 0u, 0u, 0u};
  u32x4* b4 = (u32x4*)bm2;
  for (int k = i; k < BM_WORDS / 4; k += 65536) b4[k] = z;   // 8 iters, 8 MB
}

// ---------------- K2: ONE atomic per edge: dst-major bitmap + dup detection ----------------
// bm2[g][ld][ls-bit]: row = dst (gather-ready). atomicOr's old value detects multi-edges;
// each extra occurrence pushes (ld,ls) to the per-graph dup list (preserves multiplicity).
__global__ __launch_bounds__(256) void k_build(const int* __restrict__ ei,
                                               unsigned* __restrict__ bm2,
                                               unsigned* __restrict__ dupl,
                                               int* __restrict__ dupcnt) {
  int t = blockIdx.x * 256 + threadIdx.x;          // grid 1024 -> 262144 threads, 4 edges each
  const int4* sp = (const int4*)ei;
  const int4* dp = (const int4*)(ei + NEDGE);
  int4 s4 = sp[t];
  int4 d4 = dp[t];
  int ss[4] = {s4.x, s4.y, s4.z, s4.w};
  int dd[4] = {d4.x, d4.y, d4.z, d4.w};
  #pragma unroll
  for (int q = 0; q < 4; ++q) {
    int src = ss[q], dst = dd[q];
    int gg = src >> 10, ls = src & (NPG - 1), ld = dst & (NPG - 1);
    unsigned bit = 1u << (ls & 31);
    unsigned old = atomicOr(&bm2[(size_t)(gg * NPG + ld) * 32 + (ls >> 5)], bit);
    if (old & bit) {                                // multi-edge: record extra occurrence
      int p = atomicAdd(&dupcnt[gg], 1);
      if (p < DCAP) dupl[gg * DCAP + p] = ((unsigned)ld << 16) | (unsigned)ls;
    }
  }
}

// ---------------- K3: GIN encoder (blocks 0..63) + dense_adj writing (blocks 64+) ----------------
__global__ __launch_bounds__(1024) void k_gin(
    const float* __restrict__ x, const float* __restrict__ eps,
    const unsigned* __restrict__ bm2, const unsigned* __restrict__ dupl,
    const int* __restrict__ dupcnt,
    const float* __restrict__ W0a, const float* __restrict__ b0a,
    const float* __restrict__ W0b, const float* __restrict__ b0b,
    const float* __restrict__ Wa, const float* __restrict__ ba,
    const float* __restrict__ Wb, const float* __restrict__ bb,
    const float* __restrict__ Wm, const float* __restrict__ bm_,
    const float* __restrict__ Ws, const float* __restrict__ bs,
    float* __restrict__ zbuf, float* __restrict__ acc, float* __restrict__ out) {
  __shared__ float hbuf[NPG * HSTR];            // 80 KB
  __shared__ unsigned short colc[NPG * CCAP];   // 72 KB, TRANSPOSED: colc[k*NPG + node]
  __shared__ unsigned dupl_s[DCAP];             // 4 KB
  __shared__ int ovl_s[64];                     // overflow (deg > CCAP) entries, ~never used
  __shared__ int ovn;
  __shared__ float red[16];

  if (blockIdx.x >= G) {
    // dense_adj in FINAL form from bm2 via per-chunk LDS word-column tiles (overlaps GIN work).
    // chunk c = (g, w): out rows ls = w*32..w*32+31 (128 KB); bit(ls,ld) = bm2[g][ld] >> (ls&31).
    unsigned* tw = (unsigned*)hbuf;             // 4 KB scratch
    const int tid = threadIdx.x;
    for (int c = (int)blockIdx.x - G; c < G * 32; c += (int)gridDim.x - G) {
      int g = c >> 5, w = c & 31;
      tw[tid] = bm2[(size_t)(g * NPG + tid) * 32 + w];
      __syncthreads();
      float* ob = out + 2 + (size_t)g * (NPG * NPG) + (size_t)(w * 32) * NPG;
      #pragma unroll
      for (int it = 0; it < 8; ++it) {
        int idx = tid + it * 1024;              // 0..8191 f32x4s
        int lsl = idx >> 8;                     // 0..31 (bit position = ls & 31)
        int ld0 = (idx & 255) << 2;
        u32x4 wb = *(const u32x4*)(tw + ld0);
        f32x4 v;
        v.x = ((wb.x >> lsl) & 1) ? 1.f : 0.f;
        v.y = ((wb.y >> lsl) & 1) ? 1.f : 0.f;
        v.z = ((wb.z >> lsl) & 1) ? 1.f : 0.f;
        v.w = ((wb.w >> lsl) & 1) ? 1.f : 0.f;
        __builtin_nontemporal_store(v, (f32x4*)(ob + (size_t)lsl * NPG + ld0));
      }
      __syncthreads();
    }
    return;
  }

  const int g = blockIdx.x;
  const int tid = threadIdx.x;

  // ---- prologue: stage dup list, decode own bit-row -> colc (sorted), load x -> hbuf ----
  int D = dupcnt[g];
  if (D > DCAP) D = DCAP;
  if (tid == 0) ovn = 0;
  for (int e = tid; e < D; e += 1024) dupl_s[e] = dupl[g * DCAP + e];

  {
    const float4* xg = (const float4*)(x + (size_t)g * (NPG * 16));
    for (int idx = tid; idx < NPG * 4; idx += 1024) {
      float4 v = xg[idx];
      *(float4*)(hbuf + (idx >> 2) * HSTR + (idx & 3) * 4) = v;
    }
  }
  __syncthreads();   // dupl_s + ovn ready (hbuf synced here too)

  int dv = 0;
  {
    const unsigned* myrow = bm2 + (size_t)(g * NPG + tid) * 32;
    #pragma unroll
    for (int w = 0; w < 8; ++w) {
      u32x4 w4 = *(const u32x4*)(myrow + w * 4);
      unsigned ws4[4] = {w4.x, w4.y, w4.z, w4.w};
      #pragma unroll
      for (int q = 0; q < 4; ++q) {
        unsigned m = ws4[q];
        int base = (w * 4 + q) * 32;
        while (m) {
          int b = __builtin_ctz(m); m &= m - 1;
          int ls = base + b;
          if (dv < CCAP) colc[dv * NPG + tid] = (unsigned short)ls;
          else { int p = atomicAdd(&ovn, 1); if (p < 64) ovl_s[p] = (tid << 16) | ls; }
          ++dv;
        }
      }
    }
    // append multi-edge extra occurrences (multiplicity)
    for (int e = 0; e < D; ++e) {
      unsigned ent = dupl_s[e];
      if ((int)(ent >> 16) == tid) {
        int ls = (int)(ent & (NPG - 1));
        if (dv < CCAP) colc[dv * NPG + tid] = (unsigned short)ls;
        else { int p = atomicAdd(&ovn, 1); if (p < 64) ovl_s[p] = (tid << 16) | ls; }
        ++dv;
      }
    }
  }
  const int dvl = (dv < CCAP) ? dv : CCAP;
  __syncthreads();                 // ovl_s/ovn final
  const int OV = (ovn < 64) ? ovn : 64;   // normally 0

  for (int l = 0; l < 10; ++l) {
    const float* Aw = (l == 0) ? W0a : Wa + (l - 1) * 256;
    const float* Ab = (l == 0) ? b0a : ba + (l - 1) * 16;
    const float* Bw = (l == 0) ? W0b : Wb + (l - 1) * 256;
    const float* Bb = (l == 0) ? b0b : bb + (l - 1) * 16;

    // gather: agg = h[dst] + sum_{src in N(dst)} h[src], in registers
    float4 a0 = *(const float4*)(hbuf + tid * HSTR + 0);
    float4 a1 = *(const float4*)(hbuf + tid * HSTR + 4);
    float4 a2 = *(const float4*)(hbuf + tid * HSTR + 8);
    float4 a3 = *(const float4*)(hbuf + tid * HSTR + 12);
    for (int k = 0; k < dvl; ++k) {
      int ls = colc[k * NPG + tid];              // conflict-free LDS read (lanes consecutive)
      const float* hp = hbuf + ls * HSTR;
      float4 v0 = *(const float4*)(hp + 0);
      float4 v1 = *(const float4*)(hp + 4);
      float4 v2 = *(const float4*)(hp + 8);
      float4 v3 = *(const float4*)(hp + 12);
      a0.x += v0.x; a0.y += v0.y; a0.z += v0.z; a0.w += v0.w;
      a1.x += v1.x; a1.y += v1.y; a1.z += v1.z; a1.w += v1.w;
      a2.x += v2.x; a2.y += v2.y; a2.z += v2.z; a2.w += v2.w;
      a3.x += v3.x; a3.y += v3.y; a3.z += v3.z; a3.w += v3.w;
    }
    for (int e = 0; e < OV; ++e) {               // exact overflow path (statically ~never taken)
      int ent = ovl_s[e];
      if ((ent >> 16) == tid) {
        const float* hp = hbuf + (ent & (NPG - 1)) * HSTR;
        float4 v0 = *(const float4*)(hp + 0);
        float4 v1 = *(const float4*)(hp + 4);
        float4 v2 = *(const float4*)(hp + 8);
        float4 v3 = *(const float4*)(hp + 12);
        a0.x += v0.x; a0.y += v0.y; a0.z += v0.z; a0.w += v0.w;
        a1.x += v1.x; a1.y += v1.y; a1.z += v1.z; a1.w += v1.w;
        a2.x += v2.x; a2.y += v2.y; a2.z += v2.z; a2.w += v2.w;
        a3.x += v3.x; a3.y += v3.y; a3.z += v3.z; a3.w += v3.w;
      }
    }
    float aa[16] = {a0.x, a0.y, a0.z, a0.w, a1.x, a1.y, a1.z, a1.w,
                    a2.x, a2.y, a2.z, a2.w, a3.x, a3.y, a3.z, a3.w};

    // MLP with scalar-loaded (SGPR) weights
    float u[16], v[16];
    #pragma unroll
    for (int j = 0; j < 16; ++j) u[j] = Ab[j];
    #pragma unroll
    for (int i = 0; i < 16; ++i) {
      float ai = aa[i];
      #pragma unroll
      for (int j = 0; j < 16; ++j) u[j] += ai * Aw[i * 16 + j];
    }
    #pragma unroll
    for (int j = 0; j < 16; ++j) u[j] = fmaxf(u[j], 0.f);
    #pragma unroll
    for (int j = 0; j < 16; ++j) v[j] = Bb[j];
    #pragma unroll
    for (int i = 0; i < 16; ++i) {
      float ui = u[i];
      #pragma unroll
      for (int j = 0; j < 16; ++j) v[j] += ui * Bw[i * 16 + j];
    }
    const bool rl = (l != 9);   // relu after every conv except the last
    __syncthreads();            // all gathers of old h done before overwrite
    #pragma unroll
    for (int j4 = 0; j4 < 4; ++j4) {
      float4 w;
      w.x = rl ? fmaxf(v[j4 * 4 + 0], 0.f) : v[j4 * 4 + 0];
      w.y = rl ? fmaxf(v[j4 * 4 + 1], 0.f) : v[j4 * 4 + 1];
      w.z = rl ? fmaxf(v[j4 * 4 + 2], 0.f) : v[j4 * 4 + 2];
      w.w = rl ? fmaxf(v[j4 * 4 + 3], 0.f) : v[j4 * 4 + 3];
      *(float4*)(hbuf + tid * HSTR + j4 * 4) = w;
    }
    __syncthreads();
  }

  // ---- heads: mu, std=softplus, z = mu + std*eps, KL (weights via SGPR loads) ----
  float hv[16];
  #pragma unroll
  for (int i = 0; i < 16; ++i) hv[i] = hbuf[tid * HSTR + i];  // own row, just wrote it

  float mu[8], st[8];
  #pragma unroll
  for (int m = 0; m < 8; ++m) { mu[m] = bm_[m]; st[m] = bs[m]; }
  #pragma unroll
  for (int i = 0; i < 16; ++i) {
    float hi = hv[i];
    #pragma unroll
    for (int m = 0; m < 8; ++m) { mu[m] += hi * Wm[i * 8 + m]; st[m] += hi * Ws[i * 8 + m]; }
  }
  #pragma unroll
  for (int m = 0; m < 8; ++m) {
    float s = st[m];
    st[m] = fmaxf(s, 0.f) + log1pf(__expf(-fabsf(s)));  // stable softplus, keeps tail
  }
  int gid = g * NPG + tid;
  float4 e0 = *(const float4*)(eps + (size_t)gid * 8);
  float4 e1 = *(const float4*)(eps + (size_t)gid * 8 + 4);
  float ev[8] = {e0.x, e0.y, e0.z, e0.w, e1.x, e1.y, e1.z, e1.w};
  float zv[8];
  float klp = 0.f;
  #pragma unroll
  for (int m = 0; m < 8; ++m) {
    zv[m] = mu[m] + st[m] * ev[m];
    klp += -__logf(st[m]) + 0.5f * (st[m] * st[m] + mu[m] * mu[m]) - 0.5f;
  }
  *(float4*)(zbuf + (size_t)gid * 8) = make_float4(zv[0], zv[1], zv[2], zv[3]);
  *(float4*)(zbuf + (size_t)gid * 8 + 4) = make_float4(zv[4], zv[5], zv[6], zv[7]);

  for (int o = 32; o > 0; o >>= 1) klp += __shfl_down(klp, o, 64);
  if ((tid & 63) == 0) red[tid >> 6] = klp;
  __syncthreads();
  if (tid == 0) {
    float s = 0.f;
    for (int i = 0; i < 16; ++i) s += red[i];
    atomicAdd(&acc[1], s);
  }
}

// per-element BCE term with torch's -100 clamp semantics; returns p, accumulates selected term
__device__ __forceinline__ float elem_p(float sv, int bit, float& accl) {
  float t = __expf(-sv);
  float p = __builtin_amdgcn_rcpf(1.f + t);
  float lp, lm;
  if (t > 3.0e38f)             { lp = -100.f; lm = 0.f; }     // p==0
  else if (t < 5.9604645e-08f) { lp = 0.f;    lm = -100.f; }  // p==1 (t < 2^-24)
  else { float q = __logf(1.f + t); lp = -q; lm = -sv - q; }
  accl += bit ? lp : lm;
  return p;
}

// ---------------- K4: adj_pred + full nll via bm2 word-column tile ----------------
// Transposed z-tile in LDS; bit(i,j) = bm2[g][j] word (i>>5) bit (i&31); tw[j] staged per block
// (i>>5 is block-constant since rows i0..i0+15 sit inside one 32-row word group).
__global__ __launch_bounds__(256) void k_adj(const float* __restrict__ zbuf,
                                             const unsigned* __restrict__ bm2,
                                             float* __restrict__ out,
                                             float* __restrict__ acc) {
  __shared__ float zt[8 * ZTR];   // 32.9 KB
  __shared__ unsigned tw[NPG];    // 4 KB word-column tile
  __shared__ float red[4];
  const int tid = threadIdx.x;
  const int g = blockIdx.x >> 6;
  const int i0 = (blockIdx.x & 63) << 4;

  // fill transposed tile: zt[d][j] = z[j][d]; stage bm2 word column
  {
    const float4* zg = (const float4*)(zbuf + (size_t)g * (NPG * 8));
    #pragma unroll
    for (int it = 0; it < 8; ++it) {
      int idx = tid + it * 256;            // 0..2047 float4s
      float4 v = zg[idx];
      int j = idx >> 1, db = (idx & 1) << 2;
      zt[(db + 0) * ZTR + j] = v.x;
      zt[(db + 1) * ZTR + j] = v.y;
      zt[(db + 2) * ZTR + j] = v.z;
      zt[(db + 3) * ZTR + j] = v.w;
    }
    const int wq = i0 >> 5;
    for (int idx = tid; idx < NPG; idx += 256)
      tw[idx] = bm2[(size_t)(g * NPG + idx) * 32 + wq];
  }
  __syncthreads();

  const int w = tid >> 6;    // wave 0..3 owns rows i0+4w .. i0+4w+3
  const int l = tid & 63;
  float accl = 0.f;

  for (int ir = 0; ir < 4; ++ir) {
    const int i = i0 + (w << 2) + ir;
    const int sh = i & 31;                                 // wave-uniform bit position
    float zi[8];
    #pragma unroll
    for (int d = 0; d < 8; ++d) zi[d] = zt[d * ZTR + i];   // wave-broadcast reads
    float* orow = out + 2 + (size_t)g * (NPG * NPG) + (size_t)i * NPG;
    #pragma unroll
    for (int jp = 0; jp < 4; ++jp) {
      const int j0 = (l << 2) + (jp << 8);
      float s0 = 0.f, s1 = 0.f, s2 = 0.f, s3 = 0.f;
      #pragma unroll
      for (int d = 0; d < 8; ++d) {
        float4 zr = *(const float4*)(zt + d * ZTR + j0);
        float zd = zi[d];
        s0 += zd * zr.x; s1 += zd * zr.y; s2 += zd * zr.z; s3 += zd * zr.w;
      }
      u32x4 wb = *(const u32x4*)(tw + j0);
      float p0 = elem_p(s0, (wb.x >> sh) & 1, accl);
      float p1 = elem_p(s1, (wb.y >> sh) & 1, accl);
      float p2 = elem_p(s2, (wb.z >> sh) & 1, accl);
      float p3 = elem_p(s3, (wb.w >> sh) & 1, accl);
      f32x2 v0 = {p0, p1}, v1 = {p2, p3};
      f32x2* dp = (f32x2*)(orow + j0);     // byte addr = 8 + 16k -> 8B aligned
      __builtin_nontemporal_store(v0, &dp[0]);
      __builtin_nontemporal_store(v1, &dp[1]);
    }
  }

  for (int o = 32; o > 0; o >>= 1) accl += __shfl_down(accl, o, 64);
  if (l == 0) red[w] = accl;
  __syncthreads();
  if (tid == 0) atomicAdd(&acc[0], red[0] + red[1] + red[2] + red[3]);
}

// ---------------- K5: finalize scalars (separate tiny launch; NO device fences) ----------------
__global__ void k_fin(const float* __restrict__ acc, float* __restrict__ out) {
  if (threadIdx.x == 0 && blockIdx.x == 0) {
    out[0] = -acc[0];   // nll
    out[1] = acc[1];    // kl
  }
}

extern "C" void kernel_launch(void* const* d_in, const int* in_sizes, int n_in,
                              void* d_out, int out_size, void* d_ws, size_t ws_size,
                              hipStream_t stream) {
  const float* x   = (const float*)d_in[0];
  const float* eps = (const float*)d_in[1];
  const int*   ei  = (const int*)d_in[2];
  // d_in[3] = num_graphs (64, hardcoded)
  const float* W0a = (const float*)d_in[4];
  const float* b0a = (const float*)d_in[5];
  const float* W0b = (const float*)d_in[6];
  const float* b0b = (const float*)d_in[7];
  const float* Wa  = (const float*)d_in[8];
  const float* ba  = (const float*)d_in[9];
  const float* Wb  = (const float*)d_in[10];
  const float* bb  = (const float*)d_in[11];
  const float* Wm  = (const float*)d_in[12];
  const float* bm  = (const float*)d_in[13];
  const float* Ws  = (const float*)d_in[14];
  const float* bs  = (const float*)d_in[15];
  float* out = (float*)d_out;

  // ws layout (16B-aligned segments)
  unsigned* bm2  = (unsigned*)d_ws;                      // 2M words = 8 MB
  unsigned* dupl = bm2 + BM_WORDS;                       // 64*1024 u32 = 256 KB
  int* dupcnt    = (int*)(dupl + G * DCAP);              // 64 ints
  float* zbuf    = (float*)(dupcnt + G);                 // 65536*8 f32 = 2 MB
  float* acc     = zbuf + (size_t)NNODES * 8;            // acc[0]=nll sum, acc[1]=kl

  k_init<<<64, 1024, 0, stream>>>(bm2, dupcnt, acc);
  k_build<<<1024, 256, 0, stream>>>(ei, bm2, dupl, dupcnt);
  k_gin<<<256, 1024, 0, stream>>>(x, eps, bm2, dupl, dupcnt,
                                  W0a, b0a, W0b, b0b, Wa, ba, Wb, bb,
                                  Wm, bm, Ws, bs, zbuf, acc, out);
  k_adj<<<4096, 256, 0, stream>>>(zbuf, bm2, out, acc);
  k_fin<<<1, 64, 0, stream>>>(acc, out);
}

// Round 6
// 321.186 us; speedup vs baseline: 1.1076x; 1.1076x over previous
//
#include <hip/hip_runtime.h>
#include <cstddef>

#define G 64
#define NPG 1024
#define NNODES 65536
#define NEDGE 1048576
#define BCAP 48                // per-node bucket capacity; deg~Poisson(16), P(>=48)~6e-11/node
#define LCAP 32                // LDS-cached col entries per node; P(deg>32)~1e-4/node -> global fallback
#define HSTR 20                // padded LDS row stride for h (floats); 80B rows, 16B aligned
#define ZTR 1028               // transposed z-tile d-row stride (floats); 16B-aligned, bank-staggered
#define ADJ_ELEMS 67108864ull  // 64*1024*1024
#define BM_WORDS 2097152       // 64 graphs * 1024*1024 bits / 32 = 8 MB bitmap

typedef float f32x4 __attribute__((ext_vector_type(4)));
typedef float f32x2 __attribute__((ext_vector_type(2)));
typedef unsigned u32x4 __attribute__((ext_vector_type(4)));

// ---------------- K1: zero bucket counts + accumulators + edge bitmap ----------------
__global__ __launch_bounds__(1024) void k_init(int* __restrict__ cnt, float* __restrict__ acc,
                                               unsigned* __restrict__ bm) {
  int i = blockIdx.x * 1024 + threadIdx.x;
  cnt[i] = 0;
  if (i < 2) acc[i] = 0.0f;
  u32x4 z = {0u, 0u, 0u, 0u};
  u32x4* b4 = (u32x4*)bm;
  for (int k = i; k < BM_WORDS / 4; k += 65536) b4[k] = z;   // 8 iters, 8 MB
}

// ---------------- K2: ONE pass over edges: bucket fill + edge bitmap ----------------
// int4-vectorized edge reads: 4 edges per thread, 2x 16B loads.
__global__ __launch_bounds__(256) void k_build(const int* __restrict__ ei,
                                               int* __restrict__ cnt,
                                               unsigned short* __restrict__ colb,
                                               unsigned* __restrict__ bm) {
  int t = blockIdx.x * 256 + threadIdx.x;          // grid 1024 -> 262144 threads, 4 edges each
  const int4* sp = (const int4*)ei;
  const int4* dp = (const int4*)(ei + NEDGE);
  int4 s4 = sp[t];
  int4 d4 = dp[t];
  int ss[4] = {s4.x, s4.y, s4.z, s4.w};
  int dd[4] = {d4.x, d4.y, d4.z, d4.w};
  #pragma unroll
  for (int q = 0; q < 4; ++q) {
    int src = ss[q], dst = dd[q];
    int p = atomicAdd(&cnt[dst], 1);
    if (p < BCAP) colb[(size_t)dst * BCAP + p] = (unsigned short)(src & (NPG - 1));
    int gg = src >> 10, ls = src & (NPG - 1), ld = dst & (NPG - 1);
    atomicOr(&bm[gg * 32768 + ls * 32 + (ld >> 5)], 1u << (ld & 31));
  }
}

// ---------------- K3: GIN encoder (blocks 0..63) + dense_adj writing (blocks 64+) ----------------
__global__ __launch_bounds__(1024) void k_gin(
    const float* __restrict__ x, const float* __restrict__ eps,
    const int* __restrict__ cnt, const unsigned short* __restrict__ colb,
    const float* __restrict__ W0a, const float* __restrict__ b0a,
    const float* __restrict__ W0b, const float* __restrict__ b0b,
    const float* __restrict__ Wa, const float* __restrict__ ba,
    const float* __restrict__ Wb, const float* __restrict__ bb,
    const float* __restrict__ Wm, const float* __restrict__ bm_,
    const float* __restrict__ Ws, const float* __restrict__ bs,
    const unsigned* __restrict__ ebm,
    float* __restrict__ zbuf, float* __restrict__ acc, float* __restrict__ out) {
  __shared__ float hbuf[NPG * HSTR];            // 80 KB
  __shared__ unsigned short colc[NPG * LCAP];   // 64 KB, TRANSPOSED: colc[k*NPG + node]
  __shared__ float red[16];

  if (blockIdx.x >= G) {
    // write final dense_adj from bitmap (overlaps with GIN work)
    f32x4* dz = (f32x4*)(out + 2 + ADJ_ELEMS);
    size_t i = (size_t)(blockIdx.x - G) * 1024 + threadIdx.x;
    size_t stride = (size_t)(gridDim.x - G) * 1024;
    for (; i < ADJ_ELEMS / 4; i += stride) {
      unsigned w = ebm[i >> 3];
      int sh = ((int)i & 7) << 2;
      f32x4 v;
      v.x = ((w >> (sh + 0)) & 1) ? 1.f : 0.f;
      v.y = ((w >> (sh + 1)) & 1) ? 1.f : 0.f;
      v.z = ((w >> (sh + 2)) & 1) ? 1.f : 0.f;
      v.w = ((w >> (sh + 3)) & 1) ? 1.f : 0.f;
      __builtin_nontemporal_store(v, &dz[i]);
    }
    return;
  }

  const int g = blockIdx.x;
  const int tid = threadIdx.x;
  const int dv0 = cnt[g * NPG + tid];
  const int dv = (dv0 < BCAP) ? dv0 : BCAP;     // never triggers for this input
  const int dvl = (dv < LCAP) ? dv : LCAP;      // LDS-cached portion
  const unsigned short* cl = colb + (size_t)(g * NPG + tid) * BCAP;  // global fallback (k>=LCAP)

  // cache own node's first 32 col entries into transposed LDS (own column -> no barrier needed)
  {
    const uint4* rowp = (const uint4*)(colb + (size_t)(g * NPG + tid) * BCAP);  // 96B rows, 16B aligned
    #pragma unroll
    for (int q = 0; q < 4; ++q) {
      uint4 w4 = rowp[q];
      unsigned ws0 = w4.x, ws1 = w4.y, ws2 = w4.z, ws3 = w4.w;
      colc[(q * 8 + 0) * NPG + tid] = (unsigned short)(ws0 & 0xffff);
      colc[(q * 8 + 1) * NPG + tid] = (unsigned short)(ws0 >> 16);
      colc[(q * 8 + 2) * NPG + tid] = (unsigned short)(ws1 & 0xffff);
      colc[(q * 8 + 3) * NPG + tid] = (unsigned short)(ws1 >> 16);
      colc[(q * 8 + 4) * NPG + tid] = (unsigned short)(ws2 & 0xffff);
      colc[(q * 8 + 5) * NPG + tid] = (unsigned short)(ws2 >> 16);
      colc[(q * 8 + 6) * NPG + tid] = (unsigned short)(ws3 & 0xffff);
      colc[(q * 8 + 7) * NPG + tid] = (unsigned short)(ws3 >> 16);
    }
  }

  // load x -> hbuf (h0 = x)
  {
    const float4* xg = (const float4*)(x + (size_t)g * (NPG * 16));
    for (int idx = tid; idx < NPG * 4; idx += 1024) {
      float4 v = xg[idx];
      *(float4*)(hbuf + (idx >> 2) * HSTR + (idx & 3) * 4) = v;
    }
  }
  __syncthreads();

  for (int l = 0; l < 10; ++l) {
    const float* Aw = (l == 0) ? W0a : Wa + (l - 1) * 256;
    const float* Ab = (l == 0) ? b0a : ba + (l - 1) * 16;
    const float* Bw = (l == 0) ? W0b : Wb + (l - 1) * 256;
    const float* Bb = (l == 0) ? b0b : bb + (l - 1) * 16;

    // gather: agg = h[dst] + sum_{src in N(dst)} h[src], in registers
    float4 a0 = *(const float4*)(hbuf + tid * HSTR + 0);
    float4 a1 = *(const float4*)(hbuf + tid * HSTR + 4);
    float4 a2 = *(const float4*)(hbuf + tid * HSTR + 8);
    float4 a3 = *(const float4*)(hbuf + tid * HSTR + 12);
    for (int k = 0; k < dvl; ++k) {
      int ls = colc[k * NPG + tid];              // conflict-free LDS read (lanes consecutive)
      const float* hp = hbuf + ls * HSTR;
      float4 v0 = *(const float4*)(hp + 0);
      float4 v1 = *(const float4*)(hp + 4);
      float4 v2 = *(const float4*)(hp + 8);
      float4 v3 = *(const float4*)(hp + 12);
      a0.x += v0.x; a0.y += v0.y; a0.z += v0.z; a0.w += v0.w;
      a1.x += v1.x; a1.y += v1.y; a1.z += v1.z; a1.w += v1.w;
      a2.x += v2.x; a2.y += v2.y; a2.z += v2.z; a2.w += v2.w;
      a3.x += v3.x; a3.y += v3.y; a3.z += v3.z; a3.w += v3.w;
    }
    for (int k = LCAP; k < dv; ++k) {            // rare overflow (P ~ 1e-4/node)
      int ls = cl[k];
      const float* hp = hbuf + ls * HSTR;
      float4 v0 = *(const float4*)(hp + 0);
      float4 v1 = *(const float4*)(hp + 4);
      float4 v2 = *(const float4*)(hp + 8);
      float4 v3 = *(const float4*)(hp + 12);
      a0.x += v0.x; a0.y += v0.y; a0.z += v0.z; a0.w += v0.w;
      a1.x += v1.x; a1.y += v1.y; a1.z += v1.z; a1.w += v1.w;
      a2.x += v2.x; a2.y += v2.y; a2.z += v2.z; a2.w += v2.w;
      a3.x += v3.x; a3.y += v3.y; a3.z += v3.z; a3.w += v3.w;
    }
    float aa[16] = {a0.x, a0.y, a0.z, a0.w, a1.x, a1.y, a1.z, a1.w,
                    a2.x, a2.y, a2.z, a2.w, a3.x, a3.y, a3.z, a3.w};

    // MLP with scalar-loaded (SGPR) weights
    float u[16], v[16];
    #pragma unroll
    for (int j = 0; j < 16; ++j) u[j] = Ab[j];
    #pragma unroll
    for (int i = 0; i < 16; ++i) {
      float ai = aa[i];
      #pragma unroll
      for (int j = 0; j < 16; ++j) u[j] += ai * Aw[i * 16 + j];
    }
    #pragma unroll
    for (int j = 0; j < 16; ++j) u[j] = fmaxf(u[j], 0.f);
    #pragma unroll
    for (int j = 0; j < 16; ++j) v[j] = Bb[j];
    #pragma unroll
    for (int i = 0; i < 16; ++i) {
      float ui = u[i];
      #pragma unroll
      for (int j = 0; j < 16; ++j) v[j] += ui * Bw[i * 16 + j];
    }
    const bool rl = (l != 9);   // relu after every conv except the last
    __syncthreads();            // all gathers of old h done before overwrite
    #pragma unroll
    for (int j4 = 0; j4 < 4; ++j4) {
      float4 w;
      w.x = rl ? fmaxf(v[j4 * 4 + 0], 0.f) : v[j4 * 4 + 0];
      w.y = rl ? fmaxf(v[j4 * 4 + 1], 0.f) : v[j4 * 4 + 1];
      w.z = rl ? fmaxf(v[j4 * 4 + 2], 0.f) : v[j4 * 4 + 2];
      w.w = rl ? fmaxf(v[j4 * 4 + 3], 0.f) : v[j4 * 4 + 3];
      *(float4*)(hbuf + tid * HSTR + j4 * 4) = w;
    }
    __syncthreads();
  }

  // ---- heads: mu, std=softplus, z = mu + std*eps, KL (weights via SGPR loads) ----
  float hv[16];
  #pragma unroll
  for (int i = 0; i < 16; ++i) hv[i] = hbuf[tid * HSTR + i];  // own row, just wrote it

  float mu[8], st[8];
  #pragma unroll
  for (int m = 0; m < 8; ++m) { mu[m] = bm_[m]; st[m] = bs[m]; }
  #pragma unroll
  for (int i = 0; i < 16; ++i) {
    float hi = hv[i];
    #pragma unroll
    for (int m = 0; m < 8; ++m) { mu[m] += hi * Wm[i * 8 + m]; st[m] += hi * Ws[i * 8 + m]; }
  }
  #pragma unroll
  for (int m = 0; m < 8; ++m) {
    float s = st[m];
    st[m] = fmaxf(s, 0.f) + log1pf(__expf(-fabsf(s)));  // stable softplus, keeps tail
  }
  int gid = g * NPG + tid;
  float4 e0 = *(const float4*)(eps + (size_t)gid * 8);
  float4 e1 = *(const float4*)(eps + (size_t)gid * 8 + 4);
  float ev[8] = {e0.x, e0.y, e0.z, e0.w, e1.x, e1.y, e1.z, e1.w};
  float zv[8];
  float klp = 0.f;
  #pragma unroll
  for (int m = 0; m < 8; ++m) {
    zv[m] = mu[m] + st[m] * ev[m];
    klp += -__logf(st[m]) + 0.5f * (st[m] * st[m] + mu[m] * mu[m]) - 0.5f;
  }
  *(float4*)(zbuf + (size_t)gid * 8) = make_float4(zv[0], zv[1], zv[2], zv[3]);
  *(float4*)(zbuf + (size_t)gid * 8 + 4) = make_float4(zv[4], zv[5], zv[6], zv[7]);

  for (int o = 32; o > 0; o >>= 1) klp += __shfl_down(klp, o, 64);
  if ((tid & 63) == 0) red[tid >> 6] = klp;
  __syncthreads();
  if (tid == 0) {
    float s = 0.f;
    for (int i = 0; i < 16; ++i) s += red[i];
    atomicAdd(&acc[1], s);
  }
}

// per-element BCE term with torch's -100 clamp semantics; returns p, accumulates selected term
__device__ __forceinline__ float elem_p(float sv, int bit, float& accl) {
  float t = __expf(-sv);
  float p = __builtin_amdgcn_rcpf(1.f + t);
  float lp, lm;
  if (t > 3.0e38f)             { lp = -100.f; lm = 0.f; }     // p==0
  else if (t < 5.9604645e-08f) { lp = 0.f;    lm = -100.f; }  // p==1 (t < 2^-24)
  else { float q = __logf(1.f + t); lp = -q; lm = -sv - q; }
  accl += bit ? lp : lm;
  return p;
}

// ---------------- K4: adj_pred + full nll via bitmap ----------------
// Loop-interchanged vs R4: jp outer, 4x4 register outer-tile inner. zr (j-side) is loaded
// ONCE per jp and reused across the wave's 4 rows -> ds_read_b128 per thread 128 -> 32.
// Stores unchanged: float2 NT pairs, wave-contiguous 512B -> full 128B lines.
__global__ __launch_bounds__(256) void k_adj(const float* __restrict__ zbuf,
                                             const unsigned* __restrict__ ebm,
                                             float* __restrict__ out,
                                             float* __restrict__ acc) {
  __shared__ float zt[8 * ZTR];   // 32.9 KB
  __shared__ float red[4];
  const int tid = threadIdx.x;
  const int g = blockIdx.x >> 6;
  const int i0 = (blockIdx.x & 63) << 4;

  // fill transposed tile: zt[d][j] = z[j][d]
  {
    const float4* zg = (const float4*)(zbuf + (size_t)g * (NPG * 8));
    #pragma unroll
    for (int it = 0; it < 8; ++it) {
      int idx = tid + it * 256;            // 0..2047 float4s
      float4 v = zg[idx];
      int j = idx >> 1, db = (idx & 1) << 2;
      zt[(db + 0) * ZTR + j] = v.x;
      zt[(db + 1) * ZTR + j] = v.y;
      zt[(db + 2) * ZTR + j] = v.z;
      zt[(db + 3) * ZTR + j] = v.w;
    }
  }
  __syncthreads();

  const int w = tid >> 6;    // wave 0..3 owns rows ib..ib+3
  const int l = tid & 63;
  const int ib = i0 + (w << 2);
  float accl = 0.f;

  // preload the wave's 4 zi rows into registers (broadcast LDS reads)
  float zi[4][8];
  #pragma unroll
  for (int r = 0; r < 4; ++r)
    #pragma unroll
    for (int d = 0; d < 8; ++d) zi[r][d] = zt[d * ZTR + ib + r];

  const unsigned* bmr = ebm + g * 32768 + ib * 32;       // 4 rows of bits, +32 words each
  float* obase = out + 2 + (size_t)g * (NPG * NPG) + (size_t)ib * NPG;

  #pragma unroll
  for (int jp = 0; jp < 4; ++jp) {
    const int j0 = (l << 2) + (jp << 8);
    float4 zr[8];
    #pragma unroll
    for (int d = 0; d < 8; ++d) zr[d] = *(const float4*)(zt + d * ZTR + j0);
    #pragma unroll
    for (int r = 0; r < 4; ++r) {
      float s0 = 0.f, s1 = 0.f, s2 = 0.f, s3 = 0.f;
      #pragma unroll
      for (int d = 0; d < 8; ++d) {
        float zd = zi[r][d];
        s0 += zd * zr[d].x; s1 += zd * zr[d].y; s2 += zd * zr[d].z; s3 += zd * zr[d].w;
      }
      unsigned bits = (bmr[r * 32 + (j0 >> 5)] >> (j0 & 31)) & 15u;
      float p0 = elem_p(s0, bits & 1, accl);
      float p1 = elem_p(s1, (bits >> 1) & 1, accl);
      float p2 = elem_p(s2, (bits >> 2) & 1, accl);
      float p3 = elem_p(s3, (bits >> 3) & 1, accl);
      f32x2 v0 = {p0, p1}, v1 = {p2, p3};
      f32x2* dp = (f32x2*)(obase + (size_t)r * NPG + j0);   // 8B aligned
      __builtin_nontemporal_store(v0, &dp[0]);
      __builtin_nontemporal_store(v1, &dp[1]);
    }
  }

  for (int o = 32; o > 0; o >>= 1) accl += __shfl_down(accl, o, 64);
  if (l == 0) red[w] = accl;
  __syncthreads();
  if (tid == 0) atomicAdd(&acc[0], red[0] + red[1] + red[2] + red[3]);
}

// ---------------- K5: finalize scalars (separate tiny launch; NO device fences) ----------------
__global__ void k_fin(const float* __restrict__ acc, float* __restrict__ out) {
  if (threadIdx.x == 0 && blockIdx.x == 0) {
    out[0] = -acc[0];   // nll
    out[1] = acc[1];    // kl
  }
}

extern "C" void kernel_launch(void* const* d_in, const int* in_sizes, int n_in,
                              void* d_out, int out_size, void* d_ws, size_t ws_size,
                              hipStream_t stream) {
  const float* x   = (const float*)d_in[0];
  const float* eps = (const float*)d_in[1];
  const int*   ei  = (const int*)d_in[2];
  // d_in[3] = num_graphs (64, hardcoded)
  const float* W0a = (const float*)d_in[4];
  const float* b0a = (const float*)d_in[5];
  const float* W0b = (const float*)d_in[6];
  const float* b0b = (const float*)d_in[7];
  const float* Wa  = (const float*)d_in[8];
  const float* ba  = (const float*)d_in[9];
  const float* Wb  = (const float*)d_in[10];
  const float* bb  = (const float*)d_in[11];
  const float* Wm  = (const float*)d_in[12];
  const float* bm  = (const float*)d_in[13];
  const float* Ws  = (const float*)d_in[14];
  const float* bs  = (const float*)d_in[15];
  float* out = (float*)d_out;

  // ws layout (16B-aligned segments)
  int* cnt             = (int*)d_ws;                         // 65536 ints, 256 KB
  unsigned short* colb = (unsigned short*)(cnt + NNODES);    // 65536*48 u16 = 6 MB (rows 96B, 16B-aligned)
  float* zbuf          = (float*)(colb + (size_t)NNODES * BCAP);  // 65536*8 f32 = 2 MB
  unsigned* ebm        = (unsigned*)(zbuf + (size_t)NNODES * 8);  // 2M words = 8 MB
  float* acc           = (float*)(ebm + BM_WORDS);           // acc[0]=nll sum, acc[1]=kl

  k_init<<<64, 1024, 0, stream>>>(cnt, acc, ebm);
  k_build<<<1024, 256, 0, stream>>>(ei, cnt, colb, ebm);
  k_gin<<<256, 1024, 0, stream>>>(x, eps, cnt, colb,
                                  W0a, b0a, W0b, b0b, Wa, ba, Wb, bb,
                                  Wm, bm, Ws, bs, ebm, zbuf, acc, out);
  k_adj<<<4096, 256, 0, stream>>>(zbuf, ebm, out, acc);
  k_fin<<<1, 64, 0, stream>>>(acc, out);
}